// Round 7
// baseline (158.212 us; speedup 1.0000x reference)
//
#include <hip/hip_runtime.h>
#include <hip/hip_cooperative_groups.h>

namespace cg = cooperative_groups;

#define CAM_FL 540.0f
#define CAM_W  640
#define CAM_H  480
#define RADIUS 2
#define KSIZE  (2 * RADIUS + 1)   // 5
#define TAPS   (KSIZE * KSIZE)    // 25
#define BLK    256
#define GRID   1024               // 4 blocks/CU, co-resident for grid.sync()

typedef float floatx4 __attribute__((ext_vector_type(4)));

// Persistent cooperative kernel: zero d_out -> grid.sync -> loop over particle
// chunks (project -> block-local compaction w/ separable Gaussian -> splat).
// R2 lesson: no global counters (same-address global atomics ~28 cyc/op).
// R4/R6 lesson: splat-phase latency knobs (exp precompute already kept,
// gather pipelining, XCD swizzle) are all neutral -> this round removes the
// remaining fixed costs: the separate memset dispatch and 3128 short block
// launches (now 1024 persistent blocks x ~3 chunks each).
__global__ __launch_bounds__(BLK) void particle_project_kernel(
    const float* __restrict__ locs,        // [B, N, 3]
    const float* __restrict__ camera_pose, // [B, 3]
    const float* __restrict__ camera_rot,  // [B, 4]
    const float* __restrict__ depth,       // [B, H, W]
    float* __restrict__ out,               // [B, H, W]
    int N, int chunksPerB, int B, int out_elems)
{
#pragma clang fp contract(off)
    __shared__ float s_loc[BLK * 3];
    __shared__ int   s_iy0[BLK];
    __shared__ int   s_jx0[BLK];
    __shared__ float s_z[BLK];
    __shared__ float s_wy[BLK][KSIZE];   // stride 5: gcd(5,32)=1 -> conflict-free
    __shared__ float s_wx[BLK][KSIZE];
    __shared__ int   s_cnt;

    const int tid   = threadIdx.x;
    const int gtid  = blockIdx.x * BLK + tid;
    const int gsize = gridDim.x * BLK;

    // --- phase 0: zero the output (harness poisons d_out with 0xAA) ---
    {
        const int nv4 = out_elems >> 2;
        floatx4* out4 = (floatx4*)out;
        const floatx4 z4 = {0.0f, 0.0f, 0.0f, 0.0f};
        for (int i = gtid; i < nv4; i += gsize) out4[i] = z4;
        for (int i = (nv4 << 2) + gtid; i < out_elems; i += gsize) out[i] = 0.0f;
    }
    cg::this_grid().sync();

    // --- phase 1: persistent loop over particle chunks ---
    const int totalChunks = B * chunksPerB;
    for (int c = blockIdx.x; c < totalChunks; c += gridDim.x) {
        const int b     = c / chunksPerB;
        const int chunk = c - b * chunksPerB;
        const int n0    = chunk * BLK;
        const int nrem  = min(BLK, N - n0);

        if (tid == 0) s_cnt = 0;

        // coalesced float4 stage of this chunk's locs into LDS
        {
            const float* src = locs + ((size_t)b * N + (size_t)n0) * 3;
            const int remf = nrem * 3;
            const int nv4  = remf >> 2;
            const floatx4* src4 = (const floatx4*)src;  // 16B-aligned: N,BLK mult of 4
            for (int i = tid; i < nv4; i += BLK) {
                const floatx4 v = src4[i];
                s_loc[i * 4 + 0] = v.x; s_loc[i * 4 + 1] = v.y;
                s_loc[i * 4 + 2] = v.z; s_loc[i * 4 + 3] = v.w;
            }
            for (int i = (nv4 << 2) + tid; i < remf; i += BLK)
                s_loc[i] = src[i];
        }

        // camera params (uniform within block -> scalarized)
        const float qx_raw = camera_rot[b * 4 + 0];
        const float qy_raw = camera_rot[b * 4 + 1];
        const float qz_raw = camera_rot[b * 4 + 2];
        const float qw_raw = camera_rot[b * 4 + 3];
        const float norm2 = ((qx_raw * qx_raw + qy_raw * qy_raw) + qz_raw * qz_raw) + qw_raw * qw_raw;
        const float s = sqrtf(norm2);
        const float qx = -(qx_raw / s);
        const float qy = -(qy_raw / s);
        const float qz = -(qz_raw / s);
        const float qw =  (qw_raw / s);

        const float qx2 = qx * qx, qy2 = qy * qy, qz2 = qz * qz;
        const float qxqy = qx * qy, qxqz = qx * qz, qxqw = qx * qw;
        const float qyqz = qy * qz, qyqw = qy * qw, qzqw = qz * qw;
        const float r00 = (1.0f - 2.0f * qy2) - 2.0f * qz2;
        const float r10 = 2.0f * qxqy - 2.0f * qzqw;
        const float r20 = 2.0f * qxqz + 2.0f * qyqw;
        const float r01 = 2.0f * qxqy + 2.0f * qzqw;
        const float r11 = (1.0f - 2.0f * qx2) - 2.0f * qz2;
        const float r21 = 2.0f * qyqz - 2.0f * qxqw;
        const float r02 = 2.0f * qxqz - 2.0f * qyqw;
        const float r12 = 2.0f * qyqz + 2.0f * qxqw;
        const float r22 = (1.0f - 2.0f * qx2) - 2.0f * qy2;

        const float cpx = camera_pose[b * 3 + 0];
        const float cpy = camera_pose[b * 3 + 1];
        const float cpz = camera_pose[b * 3 + 2];

        __syncthreads();   // s_loc + s_cnt visible

        // projection from LDS (stride-3 read: 2-way bank alias = free)
        bool alive = (tid < nrem);
        float px = 0.0f, py = 0.0f, z = 0.0f;
        if (alive) {
            const float p0 = s_loc[tid * 3 + 0] - cpx;
            const float p1 = s_loc[tid * 3 + 1] - cpy;
            const float p2 = s_loc[tid * 3 + 2] - cpz;

            // p' = p . R, association order matches reference ((a+b)+c)
            const float x = (p0 * r00 + p1 * r10) + p2 * r20;
            const float y = (p0 * r01 + p1 * r11) + p2 * r21;
            z             = (p0 * r02 + p1 * r12) + p2 * r22;

            alive = (z > 0.0f);
            if (alive) {
                px = (x / z) * CAM_FL + (float)CAM_W * 0.5f;
                py = (y / z) * CAM_FL + (float)CAM_H * 0.5f;
                // float-domain frustum cull before any int conversion
                alive = (px >= -(float)RADIUS && px < (float)(CAM_W + RADIUS) &&
                         py >= -(float)RADIUS && py < (float)(CAM_H + RADIUS));
            }
        }

        // block-local compaction: ballot + rank + one LDS atomic per wave
        const unsigned long long mask = __ballot(alive);
        const int lane   = tid & 63;
        const int rank   = __popcll(mask & ((1ull << lane) - 1ull));
        const int wcount = __popcll(mask);

        int wbase_v = 0;
        if (lane == 0 && wcount > 0) wbase_v = atomicAdd(&s_cnt, wcount);
        const int wbase = __shfl(wbase_v, 0);

        if (alive) {
            const int i   = wbase + rank;
            const int iy0 = (int)floorf(py);
            const int jx0 = (int)floorf(px);
            s_iy0[i] = iy0;
            s_jx0[i] = jx0;
            s_z[i]   = z;
            // separable Gaussian: 5 row + 5 col weights per survivor
#pragma unroll
            for (int k = 0; k < KSIZE; ++k) {
                const float dyf = (float)(iy0 + k - RADIUS) - py;
                const float dxf = (float)(jx0 + k - RADIUS) - px;
                s_wy[i][k] = __expf(-(dyf * dyf) * 0.5f);
                s_wx[i][k] = __expf(-(dxf * dxf) * 0.5f);
            }
        }

        __syncthreads();

        // tap-parallel splat over this chunk's survivors
        const int ns    = s_cnt;
        const int total = ns * TAPS;
        const float* depth_b = depth + (size_t)b * (CAM_H * CAM_W);
        float*       out_b   = out   + (size_t)b * (CAM_H * CAM_W);

        for (int t = tid; t < total; t += BLK) {
            const int si  = t / TAPS;            // magic-mul const division
            const int tap = t - si * TAPS;
            const int ti  = tap / KSIZE;
            const int tj  = tap - ti * KSIZE;

            // 25 consecutive lanes share one survivor -> LDS broadcasts
            const int iy = s_iy0[si] + ti - RADIUS;
            const int jx = s_jx0[si] + tj - RADIUS;
            if ((unsigned)iy >= (unsigned)CAM_H || (unsigned)jx >= (unsigned)CAM_W)
                continue;

            const int pix = iy * CAM_W + jx;
            const float d = depth_b[pix];
            if (s_z[si] <= d) {
                const float w = s_wy[si][ti] * s_wx[si][tj];
                atomicAdd(&out_b[pix], w);
            }
        }

        __syncthreads();   // LDS reuse safety before next chunk
    }
}

extern "C" void kernel_launch(void* const* d_in, const int* in_sizes, int n_in,
                              void* d_out, int out_size, void* d_ws, size_t ws_size,
                              hipStream_t stream) {
    const float* locs        = (const float*)d_in[0];
    const float* camera_pose = (const float*)d_in[1];
    const float* camera_rot  = (const float*)d_in[2];
    const float* depth_mask  = (const float*)d_in[3];
    float* out = (float*)d_out;

    int B = in_sizes[1] / 3;             // camera_pose is [B,3]
    int N = in_sizes[0] / (3 * B);       // locs is [B,N,3]
    int chunksPerB = (N + BLK - 1) / BLK;
    int out_elems = out_size;

    void* args[] = {
        (void*)&locs, (void*)&camera_pose, (void*)&camera_rot, (void*)&depth_mask,
        (void*)&out, (void*)&N, (void*)&chunksPerB, (void*)&B, (void*)&out_elems
    };
    (void)hipLaunchCooperativeKernel((void*)particle_project_kernel,
                                     dim3(GRID, 1, 1), dim3(BLK, 1, 1),
                                     args, 0, stream);
}

// Round 8
// 99.071 us; speedup vs baseline: 1.5970x; 1.5970x over previous
//
#include <hip/hip_runtime.h>

#define CAM_FL 540.0f
#define CAM_W  640
#define CAM_H  480
#define RADIUS 2
#define KSIZE  (2 * RADIUS + 1)   // 5
#define TAPS   (KSIZE * KSIZE)    // 25
#define BLK    256
#define TILE   16                 // 16x16 pixel tiles, 256 px = 1 thread each
#define TX_N   (CAM_W / TILE)     // 40
#define TY_N   (CAM_H / TILE)     // 30
#define TILES_PER_B (TX_N * TY_N) // 1200
#define REC_OFF 65536             // records start 64KB into d_ws (counts first)

// R8: invert the scatter. R4's ~24us kernel had VALUBusy 8%/HBM 5% (R7
// profile of same inner work) -> bound by ~1.6M scattered line-transactions
// (870k depth gathers + 500k pixel atomics). Replace with tile binning:
// pass 1 projects + inserts survivors into per-16x16-tile bins (atomics
// spread over 4800 counters -- R2 lesson: ONE counter serializes at ~28cyc);
// pass 2 gathers per pixel in registers, all memory coalesced, no atomics.
// R7 lesson: many small blocks >> few persistent blocks (TLP hides latency).

// ---------------------------------------------------------------------------
// Pass 1: project + cull + bin. One thread per particle, blockIdx.y = batch.
// ---------------------------------------------------------------------------
__global__ __launch_bounds__(BLK) void project_bin_kernel(
    const float* __restrict__ locs,        // [B, N, 3]
    const float* __restrict__ camera_pose, // [B, 3]
    const float* __restrict__ camera_rot,  // [B, 4]
    const float* __restrict__ depth,       // [B, H, W]
    float* __restrict__ out,               // [B, H, W] (fallback target, pre-zeroed)
    int* __restrict__ tileCnt,             // [B*1200]
    float4* __restrict__ tileRec,          // [B*1200][CAP]
    int N, int CAP)
{
#pragma clang fp contract(off)
    const int b = blockIdx.y;
    const int n = blockIdx.x * blockDim.x + threadIdx.x;
    if (n >= N) return;

    // --- camera params (uniform within block) ---
    const float qx_raw = camera_rot[b * 4 + 0];
    const float qy_raw = camera_rot[b * 4 + 1];
    const float qz_raw = camera_rot[b * 4 + 2];
    const float qw_raw = camera_rot[b * 4 + 3];
    const float norm2 = ((qx_raw * qx_raw + qy_raw * qy_raw) + qz_raw * qz_raw) + qw_raw * qw_raw;
    const float s = sqrtf(norm2);
    const float qx = -(qx_raw / s);
    const float qy = -(qy_raw / s);
    const float qz = -(qz_raw / s);
    const float qw =  (qw_raw / s);

    const float qx2 = qx * qx, qy2 = qy * qy, qz2 = qz * qz;
    const float qxqy = qx * qy, qxqz = qx * qz, qxqw = qx * qw;
    const float qyqz = qy * qz, qyqw = qy * qw, qzqw = qz * qw;
    const float r00 = (1.0f - 2.0f * qy2) - 2.0f * qz2;
    const float r10 = 2.0f * qxqy - 2.0f * qzqw;
    const float r20 = 2.0f * qxqz + 2.0f * qyqw;
    const float r01 = 2.0f * qxqy + 2.0f * qzqw;
    const float r11 = (1.0f - 2.0f * qx2) - 2.0f * qz2;
    const float r21 = 2.0f * qyqz - 2.0f * qxqw;
    const float r02 = 2.0f * qxqz - 2.0f * qyqw;
    const float r12 = 2.0f * qyqz + 2.0f * qxqw;
    const float r22 = (1.0f - 2.0f * qx2) - 2.0f * qy2;

    const float cpx = camera_pose[b * 3 + 0];
    const float cpy = camera_pose[b * 3 + 1];
    const float cpz = camera_pose[b * 3 + 2];

    // --- particle projection ---
    const float p0 = locs[(size_t)(b * N + n) * 3 + 0] - cpx;
    const float p1 = locs[(size_t)(b * N + n) * 3 + 1] - cpy;
    const float p2 = locs[(size_t)(b * N + n) * 3 + 2] - cpz;

    // p' = p . R, association order matches reference ((a+b)+c)
    const float x = (p0 * r00 + p1 * r10) + p2 * r20;
    const float y = (p0 * r01 + p1 * r11) + p2 * r21;
    const float z = (p0 * r02 + p1 * r12) + p2 * r22;

    if (!(z > 0.0f)) return;

    const float px = (x / z) * CAM_FL + (float)CAM_W * 0.5f;
    const float py = (y / z) * CAM_FL + (float)CAM_H * 0.5f;

    // float-domain frustum cull before any int conversion
    if (!(px >= -(float)RADIUS && px < (float)(CAM_W + RADIUS) &&
          py >= -(float)RADIUS && py < (float)(CAM_H + RADIUS)))
        return;

    const int iy0 = (int)floorf(py);
    const int jx0 = (int)floorf(px);

    // tiles overlapped by the (clipped) 5x5 stamp: at most 2x2
    const int tyLo = max(0, iy0 - RADIUS) / TILE;
    const int tyHi = min(CAM_H - 1, iy0 + RADIUS) / TILE;
    const int txLo = max(0, jx0 - RADIUS) / TILE;
    const int txHi = min(CAM_W - 1, jx0 + RADIUS) / TILE;

    for (int ty = tyLo; ty <= tyHi; ++ty) {
        for (int tx = txLo; tx <= txHi; ++tx) {
            const int tileId = b * TILES_PER_B + ty * TX_N + tx;
            const int idx = atomicAdd(&tileCnt[tileId], 1);
            if (idx < CAP) {
                tileRec[(size_t)tileId * CAP + idx] = make_float4(px, py, z, 0.0f);
            } else {
                // overflow fallback: splat this tile's taps directly (rare/never)
                for (int t = 0; t < TAPS; ++t) {
                    const int ti = t / KSIZE, tj = t - (t / KSIZE) * KSIZE;
                    const int iy = iy0 + ti - RADIUS;
                    const int jx = jx0 + tj - RADIUS;
                    // (iy>>4)==ty implies 0<=iy<480 given 0<=ty<=29 (arith shift)
                    if ((iy >> 4) == ty && (jx >> 4) == tx) {
                        const size_t pix = (size_t)b * (CAM_H * CAM_W) + (size_t)iy * CAM_W + jx;
                        const float d = depth[pix];
                        if (z <= d) {
                            const float dyf = (float)iy - py;
                            const float dxf = (float)jx - px;
                            atomicAdd(&out[pix], __expf(-(dyf * dyf + dxf * dxf) * 0.5f));
                        }
                    }
                }
            }
        }
    }
}

// ---------------------------------------------------------------------------
// Pass 2: per-tile gather. One block per 16x16 tile, one thread per pixel.
// All global traffic coalesced; accumulation in a register; no atomics.
// ---------------------------------------------------------------------------
__global__ __launch_bounds__(BLK) void tile_gather_kernel(
    const float* __restrict__ depth,       // [B, H, W]
    float* __restrict__ out,               // [B, H, W]
    const int* __restrict__ tileCnt,
    const float4* __restrict__ tileRec,
    int CAP)
{
#pragma clang fp contract(off)
    __shared__ float4 sRec[BLK];

    const int tileId = blockIdx.x;
    const int b  = tileId / TILES_PER_B;
    const int r  = tileId - b * TILES_PER_B;
    const int ty = r / TX_N;
    const int tx = r - ty * TX_N;

    const int tid = threadIdx.x;
    const int iy  = ty * TILE + (tid >> 4);   // tid/16
    const int jx  = tx * TILE + (tid & 15);   // tid%16

    const size_t pix = (size_t)b * (CAM_H * CAM_W) + (size_t)iy * CAM_W + jx;
    const float d    = depth[pix];
    const float prev = out[pix];   // fallback contributions (pre-zeroed + rare atomics)

    const int cnt = min(tileCnt[tileId], CAP);
    float acc = 0.0f;

    for (int base = 0; base < cnt; base += BLK) {
        const int m = min(BLK, cnt - base);
        if (tid < m)
            sRec[tid] = tileRec[(size_t)tileId * CAP + base + tid];
        __syncthreads();

        for (int s = 0; s < m; ++s) {
            const float4 rec = sRec[s];   // broadcast read
            const int riy0 = (int)floorf(rec.y);
            const int rjx0 = (int)floorf(rec.x);
            const int di = iy - riy0;
            const int dj = jx - rjx0;
            if (di >= -RADIUS && di <= RADIUS && dj >= -RADIUS && dj <= RADIUS &&
                rec.z <= d) {
                const float dyf = (float)iy - rec.y;
                const float dxf = (float)jx - rec.x;
                acc += __expf(-(dyf * dyf + dxf * dxf) * 0.5f);
            }
        }
        __syncthreads();
    }

    out[pix] = prev + acc;
}

extern "C" void kernel_launch(void* const* d_in, const int* in_sizes, int n_in,
                              void* d_out, int out_size, void* d_ws, size_t ws_size,
                              hipStream_t stream) {
    const float* locs        = (const float*)d_in[0];
    const float* camera_pose = (const float*)d_in[1];
    const float* camera_rot  = (const float*)d_in[2];
    const float* depth_mask  = (const float*)d_in[3];
    float* out = (float*)d_out;

    const int B = in_sizes[1] / 3;             // camera_pose is [B,3]
    const int N = in_sizes[0] / (3 * B);       // locs is [B,N,3]
    const int chunks = (N + BLK - 1) / BLK;
    const int nTiles = B * TILES_PER_B;

    // workspace: [0 .. 4*nTiles) tile counters, [REC_OFF ..) float4 records
    int*    tileCnt = (int*)d_ws;
    float4* tileRec = (float4*)((char*)d_ws + REC_OFF);
    long long capLL = ((long long)ws_size - REC_OFF) / ((long long)nTiles * 16);
    int CAP = (int)(capLL < 0 ? 0 : (capLL > 4096 ? 4096 : capLL));

    // harness poisons d_out/d_ws with 0xAA before every timed launch
    (void)hipMemsetAsync(d_out, 0, (size_t)out_size * sizeof(float), stream);
    (void)hipMemsetAsync(d_ws, 0, (size_t)nTiles * sizeof(int), stream);

    dim3 block(BLK, 1, 1);
    project_bin_kernel<<<dim3(chunks, B, 1), block, 0, stream>>>(
        locs, camera_pose, camera_rot, depth_mask, out, tileCnt, tileRec, N, CAP);
    tile_gather_kernel<<<dim3(nTiles, 1, 1), block, 0, stream>>>(
        depth_mask, out, tileCnt, tileRec, CAP);
}

// Round 9
// 97.269 us; speedup vs baseline: 1.6265x; 1.0185x over previous
//
#include <hip/hip_runtime.h>

#define CAM_FL 540.0f
#define CAM_W  640
#define CAM_H  480
#define RADIUS 2
#define KSIZE  (2 * RADIUS + 1)   // 5
#define TAPS   (KSIZE * KSIZE)    // 25
#define BLK    256
#define TILE   16                 // 16x16 pixel tiles, 256 px = 1 thread each
#define TX_N   (CAM_W / TILE)     // 40
#define TY_N   (CAM_H / TILE)     // 30
#define TILES_PER_B (TX_N * TY_N) // 1200
#define REC_OFF 65536             // records start 64KB into d_ws (counts first)

// R9: tile binning (pass 1, unchanged from R8, ~8us) + tap-parallel LDS-
// accumulated gather (pass 2). R8 post-mortem: pass 2's all-records-vs-all-
// 256-pixels loop was 16M record-tests (~27us VALU); tap-parallel is ~1.6M
// items. Scattered global atomics (R1/R4's ~800k fabric RMWs, visible as
// 29.5MB WRITE_SIZE in R1) are fully replaced by block-local ds_add_f32 +
// one coalesced store per pixel.
// R2 lesson: no single-address global counters (~28cyc/op serialization).
// R7 lesson: many small blocks >> few persistent blocks.

// ---------------------------------------------------------------------------
// Pass 1: project + cull + bin. One thread per particle, blockIdx.y = batch.
// ---------------------------------------------------------------------------
__global__ __launch_bounds__(BLK) void project_bin_kernel(
    const float* __restrict__ locs,        // [B, N, 3]
    const float* __restrict__ camera_pose, // [B, 3]
    const float* __restrict__ camera_rot,  // [B, 4]
    const float* __restrict__ depth,       // [B, H, W]
    float* __restrict__ out,               // [B, H, W] (fallback target, pre-zeroed)
    int* __restrict__ tileCnt,             // [B*1200]
    float4* __restrict__ tileRec,          // [B*1200][CAP]
    int N, int CAP)
{
#pragma clang fp contract(off)
    const int b = blockIdx.y;
    const int n = blockIdx.x * blockDim.x + threadIdx.x;
    if (n >= N) return;

    // --- camera params (uniform within block) ---
    const float qx_raw = camera_rot[b * 4 + 0];
    const float qy_raw = camera_rot[b * 4 + 1];
    const float qz_raw = camera_rot[b * 4 + 2];
    const float qw_raw = camera_rot[b * 4 + 3];
    const float norm2 = ((qx_raw * qx_raw + qy_raw * qy_raw) + qz_raw * qz_raw) + qw_raw * qw_raw;
    const float s = sqrtf(norm2);
    const float qx = -(qx_raw / s);
    const float qy = -(qy_raw / s);
    const float qz = -(qz_raw / s);
    const float qw =  (qw_raw / s);

    const float qx2 = qx * qx, qy2 = qy * qy, qz2 = qz * qz;
    const float qxqy = qx * qy, qxqz = qx * qz, qxqw = qx * qw;
    const float qyqz = qy * qz, qyqw = qy * qw, qzqw = qz * qw;
    const float r00 = (1.0f - 2.0f * qy2) - 2.0f * qz2;
    const float r10 = 2.0f * qxqy - 2.0f * qzqw;
    const float r20 = 2.0f * qxqz + 2.0f * qyqw;
    const float r01 = 2.0f * qxqy + 2.0f * qzqw;
    const float r11 = (1.0f - 2.0f * qx2) - 2.0f * qz2;
    const float r21 = 2.0f * qyqz - 2.0f * qxqw;
    const float r02 = 2.0f * qxqz - 2.0f * qyqw;
    const float r12 = 2.0f * qyqz + 2.0f * qxqw;
    const float r22 = (1.0f - 2.0f * qx2) - 2.0f * qy2;

    const float cpx = camera_pose[b * 3 + 0];
    const float cpy = camera_pose[b * 3 + 1];
    const float cpz = camera_pose[b * 3 + 2];

    // --- particle projection ---
    const float p0 = locs[(size_t)(b * N + n) * 3 + 0] - cpx;
    const float p1 = locs[(size_t)(b * N + n) * 3 + 1] - cpy;
    const float p2 = locs[(size_t)(b * N + n) * 3 + 2] - cpz;

    // p' = p . R, association order matches reference ((a+b)+c)
    const float x = (p0 * r00 + p1 * r10) + p2 * r20;
    const float y = (p0 * r01 + p1 * r11) + p2 * r21;
    const float z = (p0 * r02 + p1 * r12) + p2 * r22;

    if (!(z > 0.0f)) return;

    const float px = (x / z) * CAM_FL + (float)CAM_W * 0.5f;
    const float py = (y / z) * CAM_FL + (float)CAM_H * 0.5f;

    // float-domain frustum cull before any int conversion
    if (!(px >= -(float)RADIUS && px < (float)(CAM_W + RADIUS) &&
          py >= -(float)RADIUS && py < (float)(CAM_H + RADIUS)))
        return;

    const int iy0 = (int)floorf(py);
    const int jx0 = (int)floorf(px);

    // tiles overlapped by the (clipped) 5x5 stamp: at most 2x2
    const int tyLo = max(0, iy0 - RADIUS) / TILE;
    const int tyHi = min(CAM_H - 1, iy0 + RADIUS) / TILE;
    const int txLo = max(0, jx0 - RADIUS) / TILE;
    const int txHi = min(CAM_W - 1, jx0 + RADIUS) / TILE;

    for (int ty = tyLo; ty <= tyHi; ++ty) {
        for (int tx = txLo; tx <= txHi; ++tx) {
            const int tileId = b * TILES_PER_B + ty * TX_N + tx;
            const int idx = atomicAdd(&tileCnt[tileId], 1);
            if (idx < CAP) {
                tileRec[(size_t)tileId * CAP + idx] = make_float4(px, py, z, 0.0f);
            } else {
                // overflow fallback: splat this tile's taps directly (rare/never)
                for (int t = 0; t < TAPS; ++t) {
                    const int ti = t / KSIZE, tj = t - (t / KSIZE) * KSIZE;
                    const int iy = iy0 + ti - RADIUS;
                    const int jx = jx0 + tj - RADIUS;
                    if ((iy >> 4) == ty && (jx >> 4) == tx) {
                        const size_t pix = (size_t)b * (CAM_H * CAM_W) + (size_t)iy * CAM_W + jx;
                        const float d = depth[pix];
                        if (z <= d) {
                            const float dyf = (float)iy - py;
                            const float dxf = (float)jx - px;
                            atomicAdd(&out[pix], __expf(-(dyf * dyf + dxf * dxf) * 0.5f));
                        }
                    }
                }
            }
        }
    }
}

// ---------------------------------------------------------------------------
// Pass 2: per-tile tap-parallel accumulate into LDS, one coalesced store per
// pixel. Work item = (record, tap): each record touches only its 25 taps.
// ---------------------------------------------------------------------------
__global__ __launch_bounds__(BLK) void tile_accum_kernel(
    const float* __restrict__ depth,       // [B, H, W]
    float* __restrict__ out,               // [B, H, W]
    const int* __restrict__ tileCnt,
    const float4* __restrict__ tileRec,
    int CAP)
{
#pragma clang fp contract(off)
    __shared__ float  sAcc[BLK];    // 16x16 tile accumulator
    __shared__ float  sDepth[BLK];  // 16x16 depth tile
    __shared__ float4 sRec[BLK];

    const int tileId = blockIdx.x;
    const int b  = tileId / TILES_PER_B;
    const int r  = tileId - b * TILES_PER_B;
    const int ty = r / TX_N;
    const int tx = r - ty * TX_N;
    const int tyBase = ty * TILE;
    const int txBase = tx * TILE;

    const int tid = threadIdx.x;
    const int iy  = tyBase + (tid >> 4);
    const int jx  = txBase + (tid & 15);
    const size_t pix = (size_t)b * (CAM_H * CAM_W) + (size_t)iy * CAM_W + jx;

    sDepth[tid] = depth[pix];       // coalesced (16 rows x 64B)
    sAcc[tid]   = 0.0f;

    const int cnt = min(tileCnt[tileId], CAP);
    const float4* recs = tileRec + (size_t)tileId * CAP;

    for (int base = 0; base < cnt; base += BLK) {
        const int m = min(BLK, cnt - base);
        __syncthreads();                       // sRec reuse + sAcc/sDepth init visible
        if (tid < m) sRec[tid] = recs[base + tid];
        __syncthreads();

        const int total = m * TAPS;
        for (int t = tid; t < total; t += BLK) {
            const int si  = t / TAPS;          // magic-mul const division
            const int tap = t - si * TAPS;
            const int ti  = tap / KSIZE;
            const int tj  = tap - ti * KSIZE;

            const float4 rec = sRec[si];       // 25 consecutive lanes: broadcast
            const int riy = (int)floorf(rec.y) + ti - RADIUS;
            const int rjx = (int)floorf(rec.x) + tj - RADIUS;
            const int liy = riy - tyBase;
            const int ljx = rjx - txBase;
            // tap inside THIS tile? (in-tile implies in-image; out-of-tile taps
            // are handled by the neighboring tile's copy of this record)
            if ((unsigned)liy < TILE && (unsigned)ljx < TILE) {
                const int lpix = (liy << 4) + ljx;
                if (rec.z <= sDepth[lpix]) {
                    const float dyf = (float)riy - rec.y;
                    const float dxf = (float)rjx - rec.x;
                    const float w = __expf(-(dyf * dyf + dxf * dxf) * 0.5f);
                    atomicAdd(&sAcc[lpix], w);   // ds_add_f32: block-local, no fabric
                }
            }
        }
    }

    __syncthreads();
    // prev = memset zeros + rare pass-1 overflow-fallback atomics
    out[pix] = out[pix] + sAcc[tid];
}

extern "C" void kernel_launch(void* const* d_in, const int* in_sizes, int n_in,
                              void* d_out, int out_size, void* d_ws, size_t ws_size,
                              hipStream_t stream) {
    const float* locs        = (const float*)d_in[0];
    const float* camera_pose = (const float*)d_in[1];
    const float* camera_rot  = (const float*)d_in[2];
    const float* depth_mask  = (const float*)d_in[3];
    float* out = (float*)d_out;

    const int B = in_sizes[1] / 3;             // camera_pose is [B,3]
    const int N = in_sizes[0] / (3 * B);       // locs is [B,N,3]
    const int chunks = (N + BLK - 1) / BLK;
    const int nTiles = B * TILES_PER_B;

    // workspace: [0 .. 4*nTiles) tile counters, [REC_OFF ..) float4 records
    int*    tileCnt = (int*)d_ws;
    float4* tileRec = (float4*)((char*)d_ws + REC_OFF);
    long long capLL = ((long long)ws_size - REC_OFF) / ((long long)nTiles * 16);
    int CAP = (int)(capLL < 0 ? 0 : (capLL > 4096 ? 4096 : capLL));

    // harness poisons d_out/d_ws with 0xAA before every timed launch
    (void)hipMemsetAsync(d_out, 0, (size_t)out_size * sizeof(float), stream);
    (void)hipMemsetAsync(d_ws, 0, (size_t)nTiles * sizeof(int), stream);

    dim3 block(BLK, 1, 1);
    project_bin_kernel<<<dim3(chunks, B, 1), block, 0, stream>>>(
        locs, camera_pose, camera_rot, depth_mask, out, tileCnt, tileRec, N, CAP);
    tile_accum_kernel<<<dim3(nTiles, 1, 1), block, 0, stream>>>(
        depth_mask, out, tileCnt, tileRec, CAP);
}